// Round 1
// 497.680 us; speedup vs baseline: 1.0214x; 1.0214x over previous
//
#include <hip/hip_runtime.h>
#include <math.h>

// ---------------- constants ----------------
#define SQ   256          // tokens
#define DD   2048         // model dim
#define NHD  16           // heads
#define DHD  128          // head dim
#define MLPD 8192
#define KIN  4096         // INPUT_D
#define INV_SQRT_DH 0.08838834764831845f

typedef __attribute__((ext_vector_type(8))) short bf16x8;
typedef __attribute__((ext_vector_type(4))) float f32x4;

__device__ __forceinline__ float gelu_f(float x) {
    return 0.5f * x * (1.0f + erff(x * 0.70710678118654752f));
}

// float -> bf16 round-to-nearest-even
__device__ __forceinline__ short f2bf(float f) {
    unsigned u = __float_as_uint(f);
    unsigned r = (u + 0x7fffu + ((u >> 16) & 1u)) >> 16;
    return (short)r;
}

// =====================================================================
// Split-K bf16 MFMA GEMM partial: atomicAdd(C, A[128m x KC] @ W[KC x 128n])
// 128x128 tile, 512 threads = 8 waves (2 m-halves x 4 n-quarters).
// Double-buffered LDS, ONE barrier per K-chunk, register prefetch of the
// next chunk issued before the MFMA section (loads in flight under MFMA).
// LDS layout identical chunk-XOR swizzle as the verified 64^2 kernel.
// =====================================================================
__global__ __launch_bounds__(512) void gemm128(const float* __restrict__ A,
                                               const float* __restrict__ W,
                                               float* __restrict__ C,
                                               int N, int K, int KC) {
    __shared__ short As[2][128 * 64];   // [m][k] bf16, chunk-XOR swizzled
    __shared__ short Bs[2][128 * 64];   // [n][k] bf16, chunk-XOR swizzled
    const int tid = threadIdx.x;
    const int n0 = blockIdx.x * 128, m0 = blockIdx.y * 128;
    const int kstart = blockIdx.z * KC;
    const int ln = tid & 63;
    const int wv = tid >> 6;
    const int l15 = ln & 15, q = ln >> 4;
    const int wm = wv >> 2, wn = wv & 3;     // wave tile: rows wm*64, cols wn*32

    f32x4 acc[4][2];
    #pragma unroll
    for (int mt = 0; mt < 4; mt++)
        #pragma unroll
        for (int nt = 0; nt < 2; nt++) acc[mt][nt] = (f32x4){0.f, 0.f, 0.f, 0.f};

    // staging maps: A: 4 threads/row x 4 float4; B: 4 k-groups x 16 strided
    const int am = tid >> 2, ak0 = (tid & 3) * 16;
    const int bn = tid & 127, bk0 = (tid >> 7) * 16;
    const int aw0 = am * 64 + ((((ak0 >> 3) + 0) ^ (am & 7)) * 8);
    const int aw1 = am * 64 + ((((ak0 >> 3) + 1) ^ (am & 7)) * 8);
    const int bw0 = bn * 64 + ((((bk0 >> 3) + 0) ^ (bn & 7)) * 8);
    const int bw1 = bn * 64 + ((((bk0 >> 3) + 1) ^ (bn & 7)) * 8);

    const float* aptr = A + (size_t)(m0 + am) * K + kstart + ak0;
    const float* wptr = W + (size_t)(kstart + bk0) * N + n0 + bn;

    const int nch = KC >> 6;

    float4 a[4];
    float wb[16];
    // prologue: load chunk 0
    #pragma unroll
    for (int j = 0; j < 4; j++) a[j] = *(const float4*)(aptr + 4 * j);
    #pragma unroll
    for (int j = 0; j < 16; j++) wb[j] = wptr[(size_t)j * N];
    {
        short t0[16];
        #pragma unroll
        for (int j = 0; j < 4; j++) {
            t0[4 * j]     = f2bf(a[j].x);
            t0[4 * j + 1] = f2bf(a[j].y);
            t0[4 * j + 2] = f2bf(a[j].z);
            t0[4 * j + 3] = f2bf(a[j].w);
        }
        *(bf16x8*)&As[0][aw0] = *(bf16x8*)&t0[0];
        *(bf16x8*)&As[0][aw1] = *(bf16x8*)&t0[8];
        short u0[16];
        #pragma unroll
        for (int j = 0; j < 16; j++) u0[j] = f2bf(wb[j]);
        *(bf16x8*)&Bs[0][bw0] = *(bf16x8*)&u0[0];
        *(bf16x8*)&Bs[0][bw1] = *(bf16x8*)&u0[8];
    }
    __syncthreads();

    int cur = 0;
    for (int t = 0; t < nch; t++) {
        const bool pf = (t + 1 < nch);
        if (pf) {   // issue next-chunk global loads early (hide under MFMA)
            const float* ap = aptr + (t + 1) * 64;
            #pragma unroll
            for (int j = 0; j < 4; j++) a[j] = *(const float4*)(ap + 4 * j);
            const float* wp = wptr + (size_t)(t + 1) * 64 * N;
            #pragma unroll
            for (int j = 0; j < 16; j++) wb[j] = wp[(size_t)j * N];
        }

        const short* Ab = As[cur];
        const short* Bb = Bs[cur];
        bf16x8 af[4][2], bf[2][2];
        #pragma unroll
        for (int mt = 0; mt < 4; mt++) {
            const int ar = wm * 64 + mt * 16 + l15;
            af[mt][0] = *(const bf16x8*)&Ab[ar * 64 + ((q ^ (ar & 7)) * 8)];
            af[mt][1] = *(const bf16x8*)&Ab[ar * 64 + (((q + 4) ^ (ar & 7)) * 8)];
        }
        #pragma unroll
        for (int nt = 0; nt < 2; nt++) {
            const int br = wn * 32 + nt * 16 + l15;
            bf[nt][0] = *(const bf16x8*)&Bb[br * 64 + ((q ^ (br & 7)) * 8)];
            bf[nt][1] = *(const bf16x8*)&Bb[br * 64 + (((q + 4) ^ (br & 7)) * 8)];
        }
        #pragma unroll
        for (int mt = 0; mt < 4; mt++)
            #pragma unroll
            for (int nt = 0; nt < 2; nt++) {
                acc[mt][nt] = __builtin_amdgcn_mfma_f32_16x16x32_bf16(af[mt][0], bf[nt][0], acc[mt][nt], 0, 0, 0);
                acc[mt][nt] = __builtin_amdgcn_mfma_f32_16x16x32_bf16(af[mt][1], bf[nt][1], acc[mt][nt], 0, 0, 0);
            }

        if (pf) {   // convert + store into the other buffer (no conflict with reads)
            short t1[16];
            #pragma unroll
            for (int j = 0; j < 4; j++) {
                t1[4 * j]     = f2bf(a[j].x);
                t1[4 * j + 1] = f2bf(a[j].y);
                t1[4 * j + 2] = f2bf(a[j].z);
                t1[4 * j + 3] = f2bf(a[j].w);
            }
            short* Aw = (short*)As[cur ^ 1];
            short* Bw = (short*)Bs[cur ^ 1];
            *(bf16x8*)&Aw[aw0] = *(bf16x8*)&t1[0];
            *(bf16x8*)&Aw[aw1] = *(bf16x8*)&t1[8];
            short u1[16];
            #pragma unroll
            for (int j = 0; j < 16; j++) u1[j] = f2bf(wb[j]);
            *(bf16x8*)&Bw[bw0] = *(bf16x8*)&u1[0];
            *(bf16x8*)&Bw[bw1] = *(bf16x8*)&u1[8];
        }
        __syncthreads();    // single barrier per chunk
        cur ^= 1;
    }

    #pragma unroll
    for (int mt = 0; mt < 4; mt++) {
        #pragma unroll
        for (int nt = 0; nt < 2; nt++) {
            const int col = n0 + wn * 32 + nt * 16 + l15;
            #pragma unroll
            for (int i = 0; i < 4; i++) {
                const int row = m0 + wm * 64 + mt * 16 + q * 4 + i;
                atomicAdd(&C[(size_t)row * N + col], acc[mt][nt][i]);
            }
        }
    }
}

// ---------------- epilogues ----------------
__global__ __launch_bounds__(256) void epi_pos(float* __restrict__ x,
                                               const float* __restrict__ bmap) {
    const int idx = blockIdx.x * 256 + threadIdx.x;
    const int m = idx >> 11, n = idx & 2047;
    float val = x[idx] + bmap[n];
    float jf = (float)n;
    float expo = ((n & 1) ? (jf - 1.0f) : jf) * (1.0f / 2048.0f);
    float ang = (float)m * powf(10000.0f, -expo);
    x[idx] = val + ((n & 1) ? cosf(ang) : sinf(ang));
}

__global__ __launch_bounds__(256) void epi_gelu(float* __restrict__ y,
                                                const float* __restrict__ b1) {
    const int idx = blockIdx.x * 256 + threadIdx.x;
    y[idx] = gelu_f(y[idx] + b1[idx & 8191]);
}

__global__ __launch_bounds__(256) void epi_bias(float* __restrict__ x,
                                                const float* __restrict__ b2) {
    const int idx = blockIdx.x * 256 + threadIdx.x;
    x[idx] += b2[idx & 2047];
}

// =====================================================================
// per-head QKV projection, bf16 MFMA, K=128
// =====================================================================
__global__ __launch_bounds__(256) void qkv_mfma(const float* __restrict__ h,
                                                const float* __restrict__ qw, const float* __restrict__ kw,
                                                const float* __restrict__ vw, const float* __restrict__ qb,
                                                const float* __restrict__ kb, const float* __restrict__ vb,
                                                float* __restrict__ q, float* __restrict__ k,
                                                float* __restrict__ v) {
    __shared__ short As[64 * 64];
    __shared__ short Bs[64 * 64];
    const int head = blockIdx.x, m0 = blockIdx.y * 64;
    const int type = blockIdx.z >> 1, n0 = (blockIdx.z & 1) * 64;
    const float* W; const float* B; float* O;
    if (type == 0)      { W = qw; B = qb; O = q; }
    else if (type == 1) { W = kw; B = kb; O = k; }
    else                { W = vw; B = vb; O = v; }
    W += (size_t)head * DHD * DHD;
    B += head * DHD;
    const int hoff = head * DHD;
    const int tid = threadIdx.x;
    const int wv = tid >> 6, ln = tid & 63;
    const int l15 = ln & 15, qq = ln >> 4;

    f32x4 acc[4];
    #pragma unroll
    for (int j = 0; j < 4; j++) acc[j] = (f32x4){0.f, 0.f, 0.f, 0.f};

    const int am = tid >> 2, akb = (tid & 3) * 16, ac0 = (tid & 3) * 2;
    const int bn = tid & 63, bkb = (tid >> 6) * 16, bc0 = (tid >> 6) * 2;
    short* as0 = &As[am * 64 + ((ac0 ^ (am & 7)) * 8)];
    short* as1 = &As[am * 64 + (((ac0 + 1) ^ (am & 7)) * 8)];
    short* bs0 = &Bs[bn * 64 + ((bc0 ^ (bn & 7)) * 8)];
    short* bs1 = &Bs[bn * 64 + (((bc0 + 1) ^ (bn & 7)) * 8)];
    const int arow = 16 * wv + l15;
    const short* af0 = &As[arow * 64 + ((qq ^ (arow & 7)) * 8)];
    const short* af1 = &As[arow * 64 + (((qq + 4) ^ (arow & 7)) * 8)];

    for (int kc = 0; kc < DHD; kc += 64) {
        const float* ap = h + (size_t)(m0 + am) * DD + hoff + kc + akb;
        float4 a0 = *(const float4*)ap;
        float4 a1 = *(const float4*)(ap + 4);
        float4 a2 = *(const float4*)(ap + 8);
        float4 a3 = *(const float4*)(ap + 12);
        const float* wp = W + (size_t)(kc + bkb) * DHD + n0 + bn;
        float wb[16];
        #pragma unroll
        for (int j = 0; j < 16; j++) wb[j] = wp[j * DHD];

        __syncthreads();
        {
            short t[16] = {f2bf(a0.x), f2bf(a0.y), f2bf(a0.z), f2bf(a0.w),
                           f2bf(a1.x), f2bf(a1.y), f2bf(a1.z), f2bf(a1.w),
                           f2bf(a2.x), f2bf(a2.y), f2bf(a2.z), f2bf(a2.w),
                           f2bf(a3.x), f2bf(a3.y), f2bf(a3.z), f2bf(a3.w)};
            *(bf16x8*)as0 = *(bf16x8*)&t[0];
            *(bf16x8*)as1 = *(bf16x8*)&t[8];
            short u[16];
            #pragma unroll
            for (int j = 0; j < 16; j++) u[j] = f2bf(wb[j]);
            *(bf16x8*)bs0 = *(bf16x8*)&u[0];
            *(bf16x8*)bs1 = *(bf16x8*)&u[8];
        }
        __syncthreads();

        bf16x8 fa0 = *(const bf16x8*)af0;
        bf16x8 fa1 = *(const bf16x8*)af1;
        #pragma unroll
        for (int jt = 0; jt < 4; jt++) {
            const int brow = 16 * jt + l15;
            bf16x8 fb0 = *(const bf16x8*)&Bs[brow * 64 + ((qq ^ (brow & 7)) * 8)];
            bf16x8 fb1 = *(const bf16x8*)&Bs[brow * 64 + (((qq + 4) ^ (brow & 7)) * 8)];
            acc[jt] = __builtin_amdgcn_mfma_f32_16x16x32_bf16(fa0, fb0, acc[jt], 0, 0, 0);
            acc[jt] = __builtin_amdgcn_mfma_f32_16x16x32_bf16(fa1, fb1, acc[jt], 0, 0, 0);
        }
    }
    #pragma unroll
    for (int jt = 0; jt < 4; jt++) {
        const int n = n0 + 16 * jt + l15;
        #pragma unroll
        for (int i = 0; i < 4; i++) {
            const int m = m0 + 16 * wv + qq * 4 + i;
            O[(size_t)m * DD + hoff + n] = acc[jt][i] + B[n];
        }
    }
}

// =====================================================================
// block-1 attention via MFMA: x += softmax(QK^T * scale) V
// =====================================================================
__global__ __launch_bounds__(256) void attn_mfma(const float* __restrict__ q,
                                                 const float* __restrict__ k,
                                                 const float* __restrict__ v,
                                                 float* __restrict__ x) {
    __shared__ short P[64 * 272];   // [row][col chunks xor row&7], 34.8 KB
    __shared__ short ST[9216];      // K quarter [64][136] / Vt quarter [128][72]
    const int head = blockIdx.y, r0 = blockIdx.x * 64;
    const int hoff = head * DHD;
    const int tid = threadIdx.x;
    const int wv = tid >> 6, ln = tid & 63;
    const int l15 = ln & 15, qd = ln >> 4;

    bf16x8 af[4];
    {
        const float* qp = q + (size_t)(r0 + 16 * wv + l15) * DD + hoff + qd * 8;
        #pragma unroll
        for (int s = 0; s < 4; s++) {
            float4 f0 = *(const float4*)(qp + s * 32);
            float4 f1 = *(const float4*)(qp + s * 32 + 4);
            short t[8] = {f2bf(f0.x), f2bf(f0.y), f2bf(f0.z), f2bf(f0.w),
                          f2bf(f1.x), f2bf(f1.y), f2bf(f1.z), f2bf(f1.w)};
            af[s] = *(bf16x8*)t;
        }
    }

    f32x4 sacc[16];
    #pragma unroll
    for (int i = 0; i < 16; i++) sacc[i] = (f32x4){0.f, 0.f, 0.f, 0.f};

    const int skey = tid >> 2, scol = (tid & 3) * 32;
    for (int kq = 0; kq < 4; kq++) {
        const float* kp = k + (size_t)(kq * 64 + skey) * DD + hoff + scol;
        float4 f[8];
        #pragma unroll
        for (int a = 0; a < 8; a++) f[a] = *(const float4*)(kp + a * 4);
        if (kq) __syncthreads();
        #pragma unroll
        for (int a = 0; a < 4; a++) {
            short t[8] = {f2bf(f[2*a].x), f2bf(f[2*a].y), f2bf(f[2*a].z), f2bf(f[2*a].w),
                          f2bf(f[2*a+1].x), f2bf(f[2*a+1].y), f2bf(f[2*a+1].z), f2bf(f[2*a+1].w)};
            *(bf16x8*)&ST[skey * 136 + scol + a * 8] = *(bf16x8*)t;
        }
        __syncthreads();
        #pragma unroll
        for (int nl = 0; nl < 4; nl++) {
            #pragma unroll
            for (int s = 0; s < 4; s++) {
                bf16x8 bfr = *(const bf16x8*)&ST[(nl * 16 + l15) * 136 + s * 32 + qd * 8];
                sacc[kq * 4 + nl] = __builtin_amdgcn_mfma_f32_16x16x32_bf16(af[s], bfr, sacc[kq * 4 + nl], 0, 0, 0);
            }
        }
    }

    float inv_s[4];
    #pragma unroll
    for (int i = 0; i < 4; i++) {
        float m = -1e30f;
        #pragma unroll
        for (int nt = 0; nt < 16; nt++) m = fmaxf(m, sacc[nt][i]);
        m = fmaxf(m, __shfl_xor(m, 1));
        m = fmaxf(m, __shfl_xor(m, 2));
        m = fmaxf(m, __shfl_xor(m, 4));
        m = fmaxf(m, __shfl_xor(m, 8));
        float sum = 0.f;
        #pragma unroll
        for (int nt = 0; nt < 16; nt++) {
            float e = __expf((sacc[nt][i] - m) * INV_SQRT_DH);
            sacc[nt][i] = e;
            sum += e;
        }
        sum += __shfl_xor(sum, 1);
        sum += __shfl_xor(sum, 2);
        sum += __shfl_xor(sum, 4);
        sum += __shfl_xor(sum, 8);
        inv_s[i] = 1.0f / sum;
    }
    #pragma unroll
    for (int nt = 0; nt < 16; nt++) {
        const int col = nt * 16 + l15;
        const int chunk = col >> 3, c7 = col & 7;
        #pragma unroll
        for (int i = 0; i < 4; i++) {
            const int row = 16 * wv + 4 * qd + i;
            P[row * 272 + ((chunk ^ (row & 7)) * 8) + c7] = f2bf(sacc[nt][i] * inv_s[i]);
        }
    }
    __syncthreads();

    f32x4 oacc[8];
    #pragma unroll
    for (int e = 0; e < 8; e++) oacc[e] = (f32x4){0.f, 0.f, 0.f, 0.f};

    const int ve = tid & 127, vks = (tid >> 7) * 32;
    for (int kq = 0; kq < 4; kq++) {
        float vv[32];
        #pragma unroll
        for (int j = 0; j < 32; j++)
            vv[j] = v[(size_t)(kq * 64 + vks + j) * DD + hoff + ve];
        if (kq) __syncthreads();
        #pragma unroll
        for (int c = 0; c < 4; c++) {
            short t[8];
            #pragma unroll
            for (int b = 0; b < 8; b++) t[b] = f2bf(vv[c * 8 + b]);
            const int ch = (vks >> 3) + c;
            *(bf16x8*)&ST[ve * 72 + ((ch ^ (ve & 7)) * 8)] = *(bf16x8*)t;
        }
        __syncthreads();
        #pragma unroll
        for (int s = 0; s < 2; s++) {
            const int row = 16 * wv + l15;
            const int pc = kq * 8 + s * 4 + qd;
            bf16x8 pa = *(const bf16x8*)&P[row * 272 + ((pc ^ (row & 7)) * 8)];
            #pragma unroll
            for (int et = 0; et < 8; et++) {
                const int er = et * 16 + l15;
                const int vc = s * 4 + qd;
                bf16x8 vb = *(const bf16x8*)&ST[er * 72 + ((vc ^ (er & 7)) * 8)];
                oacc[et] = __builtin_amdgcn_mfma_f32_16x16x32_bf16(pa, vb, oacc[et], 0, 0, 0);
            }
        }
    }
    #pragma unroll
    for (int et = 0; et < 8; et++) {
        const int e = et * 16 + l15;
        #pragma unroll
        for (int i = 0; i < 4; i++) {
            const int row = r0 + 16 * wv + 4 * qd + i;
            x[(size_t)row * DD + hoff + e] += oacc[et][i];
        }
    }
}

// ---------------- layernorm (one block per row); optionally zero a buffer ----------------
__global__ __launch_bounds__(256) void ln_kernel(const float* __restrict__ xin,
                                                 const float* __restrict__ g,
                                                 const float* __restrict__ b,
                                                 float* __restrict__ out,
                                                 float* __restrict__ zbuf, int zn) {
    __shared__ float red[8];
    const int tid = threadIdx.x;
    for (int i = tid; i < zn; i += 256) zbuf[i] = 0.0f;
    const int row = blockIdx.x;
    const float* xr = xin + row * DD;
    float vals[8];
    float s = 0.0f;
    #pragma unroll
    for (int i = 0; i < 8; i++) { vals[i] = xr[tid + i * 256]; s += vals[i]; }
    #pragma unroll
    for (int o = 32; o > 0; o >>= 1) s += __shfl_down(s, o);
    if ((tid & 63) == 0) red[tid >> 6] = s;
    __syncthreads();
    if (tid == 0) red[4] = (red[0] + red[1] + red[2] + red[3]) * (1.0f / 2048.0f);
    __syncthreads();
    const float mean = red[4];
    float vs = 0.0f;
    #pragma unroll
    for (int i = 0; i < 8; i++) { float d = vals[i] - mean; vs += d * d; }
    #pragma unroll
    for (int o = 32; o > 0; o >>= 1) vs += __shfl_down(vs, o);
    if ((tid & 63) == 0) red[tid >> 6] = vs;
    __syncthreads();
    if (tid == 0) red[5] = rsqrtf((red[0] + red[1] + red[2] + red[3]) * (1.0f / 2048.0f) + 1e-5f);
    __syncthreads();
    const float inv = red[5];
    #pragma unroll
    for (int i = 0; i < 8; i++) {
        int c = tid + i * 256;
        out[row * DD + c] = (vals[i] - mean) * inv * g[c] + b[c];
    }
}

// ---------------- block-2 attention, query row 0 only ----------------
__global__ __launch_bounds__(256) void attn0_kernel(const float* __restrict__ q,
                                                    const float* __restrict__ k,
                                                    const float* __restrict__ v,
                                                    float* __restrict__ x) {
    __shared__ float q0[128];
    __shared__ float p[256];
    __shared__ float red[8];
    const int h = blockIdx.x, tid = threadIdx.x, hoff = h * DHD;
    if (tid < 128) q0[tid] = q[hoff + tid];
    __syncthreads();
    const float* kr = k + tid * DD + hoff;
    float s = 0.0f;
    #pragma unroll 8
    for (int d = 0; d < 128; d++) s += q0[d] * kr[d];
    s *= INV_SQRT_DH;
    float m = s;
    #pragma unroll
    for (int o = 32; o > 0; o >>= 1) m = fmaxf(m, __shfl_down(m, o));
    if ((tid & 63) == 0) red[tid >> 6] = m;
    __syncthreads();
    if (tid == 0) red[4] = fmaxf(fmaxf(red[0], red[1]), fmaxf(red[2], red[3]));
    __syncthreads();
    const float mx = red[4];
    float e = __expf(s - mx);
    p[tid] = e;
    float t = e;
    #pragma unroll
    for (int o = 32; o > 0; o >>= 1) t += __shfl_down(t, o);
    if ((tid & 63) == 0) red[tid >> 6] = t;
    __syncthreads();
    if (tid == 0) red[5] = red[0] + red[1] + red[2] + red[3];
    __syncthreads();
    const float inv = 1.0f / red[5];
    if (tid < 128) {
        float acc = 0.0f;
        #pragma unroll 8
        for (int j = 0; j < 256; j++) acc += p[j] * v[j * DD + hoff + tid];
        x[hoff + tid] += acc * inv;
    }
}

// ---------------- block-2 MLP GEMVs (token 0 only) ----------------
__global__ __launch_bounds__(256) void gemv1_kernel(const float* __restrict__ h2,
                                                    const float* __restrict__ w1,
                                                    float* __restrict__ y) {
    const int n = blockIdx.x * 256 + threadIdx.x;
    const int k0 = blockIdx.y * 64;
    float s = 0.0f;
    #pragma unroll 8
    for (int k = 0; k < 64; k++) s += h2[k0 + k] * w1[(size_t)(k0 + k) * MLPD + n];
    atomicAdd(&y[n], s);
}

__global__ __launch_bounds__(256) void gelu_bias_kernel(float* __restrict__ y,
                                                        const float* __restrict__ b1) {
    const int n = blockIdx.x * 256 + threadIdx.x;
    y[n] = gelu_f(y[n] + b1[n]);
}

__global__ __launch_bounds__(256) void gemv2_kernel(const float* __restrict__ y1,
                                                    const float* __restrict__ w2,
                                                    float* __restrict__ x) {
    const int m = blockIdx.x * 256 + threadIdx.x;
    const int k0 = blockIdx.y * 256;
    float s = 0.0f;
    #pragma unroll 8
    for (int k = 0; k < 256; k++) s += y1[k0 + k] * w2[(size_t)(k0 + k) * DD + m];
    atomicAdd(&x[m], s);
}

// ---------------- head: sigmoid(cls . head_w + head_b), copy memory ----------------
__global__ __launch_bounds__(256) void head_kernel(const float* __restrict__ x,
                                                   const float* __restrict__ b2l,
                                                   const float* __restrict__ hw,
                                                   const float* __restrict__ hb,
                                                   const float* __restrict__ mem,
                                                   float* __restrict__ out) {
    __shared__ float red[8];
    const int tid = threadIdx.x;
    float s = 0.0f;
    for (int m = tid; m < 2048; m += 256) s += (x[m] + b2l[m]) * hw[m];
    #pragma unroll
    for (int o = 32; o > 0; o >>= 1) s += __shfl_down(s, o);
    if ((tid & 63) == 0) red[tid >> 6] = s;
    __syncthreads();
    if (tid == 0) {
        float t = red[0] + red[1] + red[2] + red[3];
        out[0] = 1.0f / (1.0f + __expf(-(t + hb[0])));
    }
    if (tid < 8) out[1 + tid] = mem[tid];
}

extern "C" void kernel_launch(void* const* d_in, const int* in_sizes, int n_in,
                              void* d_out, int out_size, void* d_ws, size_t ws_size,
                              hipStream_t stream) {
    const float* images = (const float*)d_in[0];
    const float* memory = (const float*)d_in[1];
    const float* wmap   = (const float*)d_in[2];
    const float* bmap   = (const float*)d_in[3];
    const float* ln1_g  = (const float*)d_in[4];
    const float* ln1_b  = (const float*)d_in[5];
    const float* qw     = (const float*)d_in[6];
    const float* qb     = (const float*)d_in[7];
    const float* kw     = (const float*)d_in[8];
    const float* kb     = (const float*)d_in[9];
    const float* vw     = (const float*)d_in[10];
    const float* vb     = (const float*)d_in[11];
    const float* ln2_g  = (const float*)d_in[12];
    const float* ln2_b  = (const float*)d_in[13];
    const float* w1     = (const float*)d_in[14];
    const float* b1     = (const float*)d_in[15];
    const float* w2     = (const float*)d_in[16];
    const float* b2     = (const float*)d_in[17];
    const float* head_w = (const float*)d_in[18];
    const float* head_b = (const float*)d_in[19];
    float* out = (float*)d_out;

    float* ws = (float*)d_ws;
    float* x     = ws;                    // 256*2048
    float* h     = x + SQ * DD;           // 256*2048
    float* q     = h + SQ * DD;           // 256*2048
    float* k     = q + SQ * DD;
    float* v     = k + SQ * DD;
    float* y1    = v + SQ * DD;           // 256*8192
    float* y1row = y1 + SQ * MLPD;        // 8192
    float* h2row = y1row + MLPD;          // 2048

    // ---- patch embed: x = images @ wmap (split-K atomic) + bias + posemb ----
    hipMemsetAsync(x, 0, (size_t)SQ * DD * sizeof(float), stream);
    gemm128<<<dim3(DD / 128, SQ / 128, 8), 512, 0, stream>>>(images, wmap, x, DD, KIN, 512);
    epi_pos<<<SQ * DD / 256, 256, 0, stream>>>(x, bmap);

    for (int l = 0; l < 2; l++) {
        const size_t wofs = (size_t)l * NHD * DHD * DHD;
        const size_t bofs = (size_t)l * NHD * DHD;
        ln_kernel<<<SQ, 256, 0, stream>>>(x, ln1_g + l * DD, ln1_b + l * DD, h, nullptr, 0);
        qkv_mfma<<<dim3(NHD, SQ / 64, 6), 256, 0, stream>>>(h, qw + wofs, kw + wofs, vw + wofs,
                                                            qb + bofs, kb + bofs, vb + bofs,
                                                            q, k, v);
        if (l == 0) {
            attn_mfma<<<dim3(SQ / 64, NHD), 256, 0, stream>>>(q, k, v, x);
            ln_kernel<<<SQ, 256, 0, stream>>>(x, ln2_g, ln2_b, h, nullptr, 0);
            // MLP1: y1 = gelu(h @ w1 + b1)
            hipMemsetAsync(y1, 0, (size_t)SQ * MLPD * sizeof(float), stream);
            gemm128<<<dim3(MLPD / 128, SQ / 128, 2), 512, 0, stream>>>(h, w1, y1, MLPD, DD, 1024);
            epi_gelu<<<SQ * MLPD / 256, 256, 0, stream>>>(y1, b1);
            // MLP2: x += y1 @ w2 + b2
            gemm128<<<dim3(DD / 128, SQ / 128, 8), 512, 0, stream>>>(y1, w2, x, DD, MLPD, 1024);
            epi_bias<<<SQ * DD / 256, 256, 0, stream>>>(x, b2);
        } else {
            attn0_kernel<<<NHD, 256, 0, stream>>>(q, k, v, x);
            ln_kernel<<<1, 256, 0, stream>>>(x, ln2_g + DD, ln2_b + DD, h2row, y1row, MLPD);
            gemv1_kernel<<<dim3(MLPD / 256, 32), 256, 0, stream>>>(h2row, w1 + (size_t)DD * MLPD, y1row);
            gelu_bias_kernel<<<MLPD / 256, 256, 0, stream>>>(y1row, b1 + MLPD);
            gemv2_kernel<<<dim3(DD / 256, 32), 256, 0, stream>>>(y1row, w2 + (size_t)DD * MLPD, x);
            head_kernel<<<1, 256, 0, stream>>>(x, b2 + DD, head_w, head_b, memory, out);
        }
    }
}